// Round 8
// baseline (114.184 us; speedup 1.0000x reference)
//
#include <hip/hip_runtime.h>

// ---------------------------------------------------------------------------
// Joint network: y = relu(f@W1t^T + g@W1p^T + (b1t+b1p)) @ W2^T + b2
// N=32768, K1=1344 (1024 f + 320 g), J=512, KOUT=29. fp32 in/out, bf16 MFMA.
// R8: R5 geometry (BM=64, 8 waves, 64x64 wave tile, 2 blocks/CU) with the
//     scheduler UNSHACKLED: no sched_barrier, no explicit vmcnt. B from L2
//     to registers prefetched 1 step ahead; A reg ring depth 3; LDS = 16 KB
//     (A only). Raw s_barrier + lgkmcnt(0) so reg prefetches live across it.
// ---------------------------------------------------------------------------

typedef float  f32x4  __attribute__((ext_vector_type(4)));
typedef short  s16x8  __attribute__((ext_vector_type(8)));   // 8 bf16
typedef short  s16x4  __attribute__((ext_vector_type(4)));   // 4 bf16

#define N_ROWS   32768
#define NKS      42            // K1 / 32
#define KOUT     29

#define WC_ELEMS   (NKS * 4 * 512 * 8)   // 688128 bf16: [ks][kc][j][8]
#define W2C_ELEMS  (64 * 32 * 8)         // 16384 bf16:  [jc][kout32][8]

#define LGKM0()    asm volatile("s_waitcnt lgkmcnt(0)" ::: "memory")
#define SBAR()     __builtin_amdgcn_s_barrier()
#define PRIO(n)    __builtin_amdgcn_s_setprio(n)

static __device__ __forceinline__ unsigned short f2bf(float x) {
  union { float f; unsigned u; } v; v.f = x;
  unsigned r = v.u + 0x7fffu + ((v.u >> 16) & 1u);   // RNE
  return (unsigned short)(r >> 16);
}

// ---------------------------------------------------------------------------
__global__ __launch_bounds__(512) void prep_kernel(
    const float* __restrict__ W1t, const float* __restrict__ b1t,
    const float* __restrict__ W1p, const float* __restrict__ b1p,
    const float* __restrict__ W2,  const float* __restrict__ b2,
    unsigned short* __restrict__ Wc, unsigned short* __restrict__ W2c,
    float* __restrict__ bc, float* __restrict__ b2c) {
  int idx = blockIdx.x * 512 + threadIdx.x;
  if (idx < WC_ELEMS) {
    int e  = idx & 7;
    int j  = (idx >> 3) & 511;
    int kc = (idx >> 12) & 3;
    int ks = idx >> 14;
    int c  = ks * 32 + kc * 8 + e;
    float v = (c < 1024) ? W1t[j * 1024 + c] : W1p[j * 320 + (c - 1024)];
    Wc[idx] = f2bf(v);
  }
  if (idx < W2C_ELEMS) {
    int e  = idx & 7;
    int ko = (idx >> 3) & 31;
    int jc = idx >> 8;
    int j  = jc * 8 + e;
    float v = (ko < KOUT) ? W2[ko * 512 + j] : 0.0f;
    W2c[idx] = f2bf(v);
  }
  if (idx < 512) bc[idx]  = b1t[idx] + b1p[idx];
  if (idx < 32)  b2c[idx] = (idx < KOUT) ? b2[idx] : 0.0f;
}

// ---------------------------------------------------------------------------
// 512 blocks x 512 threads (8 waves, 2 blocks/CU). Block tile 64 x 512.
// Wave w: 64 rows x cols [w*64,(w+1)*64): 4m x 4n of 16x16 tiles.
// LDS: A dbuf [2][4kc][64row][8] bf16 @0  (8 KB, XOR-swizzled)
//      phase2 h-chunk [16pl][64r][8] @0   (16 KB, aliases A)
// Total 16 KB. B: global(L2)->regs, prefetched 1 step ahead. No vmcnt asm.
// ---------------------------------------------------------------------------
__global__ __launch_bounds__(512, 4) void joint_kernel(
    const float* __restrict__ f, const float* __restrict__ g,
    const unsigned short* __restrict__ Wc, const unsigned short* __restrict__ W2c,
    const float* __restrict__ bc, const float* __restrict__ b2c,
    float* __restrict__ out) {
  __shared__ __align__(16) char smem[16384];

  const int tid = threadIdx.x;
  const int l   = tid & 63;
  const int w   = tid >> 6;          // wave 0..7 (col slice w*64)
  const int m0  = blockIdx.x * 64;

  // A staging: row = tid>>3 (64 rows), kq = tid&7 (8 x f32x4 = 32 k)
  const int srow = tid >> 3;
  const int kq   = tid & 7;
  const char* fA = (const char*)(f + (size_t)(m0 + srow) * 1024 + kq * 4);
  const char* gA = (const char*)(g + (size_t)(m0 + srow) * 320  + kq * 4);
  const int kcpl = kq >> 1;
  const unsigned a_wr = (unsigned)(kcpl * 1024 +
      ((srow * 16 + (kq & 1) * 8) ^ (kcpl << 5)));

  // fragment read offsets
  const int kcg = l >> 4;            // 0..3
  const int lc  = l & 15;
  const unsigned a_rd = (unsigned)(kcg * 1024 + ((lc * 16) ^ (kcg << 5)));
  // B global base: j = w*64 + n*16 + lc, k-chunk kcg
  const char* WbT = (const char*)Wc + kcg * 8192 + (w * 64 + lc) * 16;

  f32x4 acc[4][4];
#pragma unroll
  for (int m = 0; m < 4; m++)
#pragma unroll
    for (int n = 0; n < 4; n++) acc[m][n] = (f32x4)(0.0f);

  f32x4 pa0, pa1, pa2;     // A prefetch ring, depth 3: A(X) lives in pa[X%3]
  s16x8 bqE[4], bqO[4];    // B ping-pong: B(even T) in bqE, B(odd T) in bqO

#define ISSUE_B(DST, T) {                                                   \
    const char* pb_ = WbT + (size_t)(T) * 32768;                            \
    _Pragma("unroll")                                                       \
    for (int n_ = 0; n_ < 4; n_++)                                          \
      DST[n_] = *(const s16x8*)(pb_ + n_ * 256);                            \
  }

#define STAGE_A(BUF, SRCREG) {                                              \
    s16x4 hv;                                                               \
    hv[0] = (short)f2bf(SRCREG[0]); hv[1] = (short)f2bf(SRCREG[1]);         \
    hv[2] = (short)f2bf(SRCREG[2]); hv[3] = (short)f2bf(SRCREG[3]);         \
    *(s16x4*)(smem + (BUF) * 4096 + a_wr) = hv;                             \
  }

  // Step T: issue B(T+1)->BQN and A(T+3)->PISSU early; ds_read A frags of
  // buf T&1; 16 MFMA vs BQC; stage A(T+1) from PCONS; lgkm0 + barrier.
  // No sched_barrier / no explicit vmcnt: compiler interleaves ds_reads
  // under MFMAs and emits exact counted waits for the reg prefetches.
#define K_STEP(T, BQC, BQN, PCONS, PISSU, DO_B, DO_A, ASRC, DO_WR) {        \
    if (DO_B) { ISSUE_B(BQN, (T) + 1); }                                    \
    if (DO_A) { PISSU = *(const f32x4*)(ASRC); }                            \
    s16x8 af[4];                                                            \
    _Pragma("unroll")                                                       \
    for (int m = 0; m < 4; m++)                                             \
      af[m] = *(const s16x8*)(smem + ((T) & 1) * 4096 + a_rd + m * 256);    \
    PRIO(1);                                                                \
    _Pragma("unroll")                                                       \
    for (int m = 0; m < 4; m++)                                             \
      _Pragma("unroll")                                                     \
      for (int n = 0; n < 4; n++)                                           \
        acc[m][n] = __builtin_amdgcn_mfma_f32_16x16x32_bf16(                \
            af[m], BQC[n], acc[m][n], 0, 0, 0);                             \
    PRIO(0);                                                                \
    if (DO_WR) { STAGE_A(((T) + 1) & 1, PCONS); }                           \
    LGKM0();                                                                \
    SBAR();                                                                 \
  }

  // ---- prologue: B(0)->bqE; A(0),A(1),A(2)->ring; stage A(0) ----
  ISSUE_B(bqE, 0);
  pa0 = *(const f32x4*)(fA);           // A(0)
  pa1 = *(const f32x4*)(fA + 128);     // A(1)
  pa2 = *(const f32x4*)(fA + 256);     // A(2)
  STAGE_A(0, pa0);                     // compiler waits exactly for pa0
  LGKM0();
  SBAR();

  // ---- K loop: T=0..41. A(T+3) src: f for T<=28, g for 29<=T<=38 ----
  for (int tb = 0; tb < 24; tb += 6) {
    K_STEP(tb + 0, bqE, bqO, pa1, pa0, 1, 1, fA + (tb + 3) * 128, 1);
    K_STEP(tb + 1, bqO, bqE, pa2, pa1, 1, 1, fA + (tb + 4) * 128, 1);
    K_STEP(tb + 2, bqE, bqO, pa0, pa2, 1, 1, fA + (tb + 5) * 128, 1);
    K_STEP(tb + 3, bqO, bqE, pa1, pa0, 1, 1, fA + (tb + 6) * 128, 1);
    K_STEP(tb + 4, bqE, bqO, pa2, pa1, 1, 1, fA + (tb + 7) * 128, 1);
    K_STEP(tb + 5, bqO, bqE, pa0, pa2, 1, 1, fA + (tb + 8) * 128, 1);
  }
  K_STEP(24, bqE, bqO, pa1, pa0, 1, 1, fA + 27 * 128, 1);
  K_STEP(25, bqO, bqE, pa2, pa1, 1, 1, fA + 28 * 128, 1);
  K_STEP(26, bqE, bqO, pa0, pa2, 1, 1, fA + 29 * 128, 1);
  K_STEP(27, bqO, bqE, pa1, pa0, 1, 1, fA + 30 * 128, 1);
  K_STEP(28, bqE, bqO, pa2, pa1, 1, 1, fA + 31 * 128, 1);
  K_STEP(29, bqO, bqE, pa0, pa2, 1, 1, gA + 0 * 128, 1);
  K_STEP(30, bqE, bqO, pa1, pa0, 1, 1, gA + 1 * 128, 1);
  K_STEP(31, bqO, bqE, pa2, pa1, 1, 1, gA + 2 * 128, 1);
  K_STEP(32, bqE, bqO, pa0, pa2, 1, 1, gA + 3 * 128, 1);
  K_STEP(33, bqO, bqE, pa1, pa0, 1, 1, gA + 4 * 128, 1);
  K_STEP(34, bqE, bqO, pa2, pa1, 1, 1, gA + 5 * 128, 1);
  K_STEP(35, bqO, bqE, pa0, pa2, 1, 1, gA + 6 * 128, 1);
  K_STEP(36, bqE, bqO, pa1, pa0, 1, 1, gA + 7 * 128, 1);
  K_STEP(37, bqO, bqE, pa2, pa1, 1, 1, gA + 8 * 128, 1);
  K_STEP(38, bqE, bqO, pa0, pa2, 1, 1, gA + 9 * 128, 1);   // A(41): last
  K_STEP(39, bqO, bqE, pa1, pa0, 1, 0, gA, 1);             // stage A(40)
  K_STEP(40, bqE, bqO, pa2, pa1, 1, 0, gA, 1);             // B(41); stage A(41)
  K_STEP(41, bqO, bqE, pa0, pa2, 0, 0, gA, 0);

  // ---- phase 2: y = relu(h+bias) @ W2^T + b2, h streamed in 4 chunks ----
  // Chunk p: j in [p*128,(p+1)*128), written by waves 2p,2p+1. Then all 8
  // waves MFMA: wave w owns y rows (w&3)*16.., ko (w>>2)*16.. W2 from L2.
  float bias[4];
#pragma unroll
  for (int n = 0; n < 4; n++) bias[n] = bc[w * 64 + n * 16 + lc];

  f32x4 acc2 = (f32x4)(0.0f);
  const int myw = w >> 1;
  const int ko  = (w >> 2) * 16 + lc;
  const unsigned h_rdrow = (unsigned)(((w & 3) * 16 + lc) * 16);

#pragma unroll
  for (int p = 0; p < 4; p++) {
    __syncthreads();                 // h chunk region free
    if (myw == p) {
#pragma unroll
      for (int n = 0; n < 4; n++) {
        const int jrel  = (w & 1) * 64 + n * 16 + lc;
        const int plane = jrel >> 3;
        const unsigned wswz = (unsigned)((plane & 3) << 5);
#pragma unroll
        for (int m = 0; m < 4; m++)
#pragma unroll
          for (int r = 0; r < 4; r++) {
            float v = fmaxf(acc[m][n][r] + bias[n], 0.0f);
            const unsigned rowh = (unsigned)(m * 16 + kcg * 4 + r);
            *(unsigned short*)(smem + plane * 1024 +
                ((rowh * 16 + (jrel & 7) * 2) ^ wswz)) = f2bf(v);
          }
      }
    }
    __syncthreads();
    s16x8 wfv[4];
#pragma unroll
    for (int ks2 = 0; ks2 < 4; ks2++)
      wfv[ks2] = *(const s16x8*)((const char*)W2c +
                   (p * 16 + ks2 * 4 + kcg) * 512 + ko * 16);
#pragma unroll
    for (int ks2 = 0; ks2 < 4; ks2++) {
      const int plane = ks2 * 4 + kcg;
      s16x8 hf = *(const s16x8*)(smem + plane * 1024 +
                                 (h_rdrow ^ ((unsigned)(plane & 3) << 5)));
      acc2 = __builtin_amdgcn_mfma_f32_16x16x32_bf16(hf, wfv[ks2], acc2, 0, 0, 0);
    }
  }

  // ---- epilogue: +b2, store (29 of 32 cols) ----
  if (ko < KOUT) {
    const float bb = b2c[ko];
    const int orow0 = m0 + (w & 3) * 16 + kcg * 4;
#pragma unroll
    for (int r = 0; r < 4; r++)
      out[(size_t)(orow0 + r) * KOUT + ko] = acc2[r] + bb;
  }

#undef ISSUE_B
#undef STAGE_A
#undef K_STEP
}

// ---------------------------------------------------------------------------
extern "C" void kernel_launch(void* const* d_in, const int* in_sizes, int n_in,
                              void* d_out, int out_size, void* d_ws, size_t ws_size,
                              hipStream_t stream) {
  const float* f   = (const float*)d_in[0];
  const float* g   = (const float*)d_in[1];
  const float* W1t = (const float*)d_in[2];
  const float* b1t = (const float*)d_in[3];
  const float* W1p = (const float*)d_in[4];
  const float* b1p = (const float*)d_in[5];
  const float* W2  = (const float*)d_in[6];
  const float* b2  = (const float*)d_in[7];
  float* out = (float*)d_out;

  unsigned short* Wc  = (unsigned short*)d_ws;
  unsigned short* W2c = Wc + WC_ELEMS;
  float* bcp  = (float*)(W2c + W2C_ELEMS);
  float* b2cp = bcp + 512;

  prep_kernel<<<WC_ELEMS / 512, 512, 0, stream>>>(W1t, b1t, W1p, b1p, W2, b2,
                                                  Wc, W2c, bcp, b2cp);
  joint_kernel<<<N_ROWS / 64, 512, 0, stream>>>(f, g, Wc, W2c, bcp, b2cp, out);
}